// Round 8
// baseline (1250.080 us; speedup 1.0000x reference)
//
#include <hip/hip_runtime.h>
#include <math.h>

// Problem constants
#define DD 256            // latent dim
#define KK 8192           // codebook size
#define NN 16384          // 16 * 1024 rows
#define MT 64             // rows per block (4 waves x 16 rows/thread)
#define NT 512            // codebook cols per chunk (lane + 64*j, j 0..7)
#define NCH (KK / NT)     // 16 chunks
#define DT 16             // d-slice floats
#define NDT (DD / DT)     // 16 d-slices per chunk
#define NEPOCH (NCH * NDT)  // 256
#define NBLOCKS (NN / MT) // 256
#define CBUF 8192         // floats per C buffer (512 rows x 16)
#define RSTRIDE 260       // rowsumsq staging stride (unchanged, verified)

// Output layout (all float32, concatenated in reference return order)
#define OUT_IDS   0
#define OUT_Q     16384
#define OUT_ST    4210688          // 16384 + 4194304
#define OUT_COMMIT 8404992
#define OUT_CBL    8404993
#define OUT_PERP   8404994

// ---------------------------------------------------------------------------
// async global->LDS DMA: lane i's 16B lands at ldsbase + i*16 (contiguous 1KB).
// Global source address is PER-LANE -> layout swizzles live on the source side.
// ---------------------------------------------------------------------------
__device__ __forceinline__ void gl2lds16(const float* g, float* l) {
    __builtin_amdgcn_global_load_lds(
        (const __attribute__((address_space(1))) float*)g,
        (__attribute__((address_space(3))) float*)l, 16, 0, 0);
}

// ---------------------------------------------------------------------------
// numpy pairwise-sum replica for sum of squares (verified bit-exact, round 2)
// ---------------------------------------------------------------------------
__device__ __forceinline__ float np_block128_sumsq(const float* p) {
    #pragma clang fp contract(off)
    float r0 = p[0] * p[0], r1 = p[1] * p[1], r2 = p[2] * p[2], r3 = p[3] * p[3];
    float r4 = p[4] * p[4], r5 = p[5] * p[5], r6 = p[6] * p[6], r7 = p[7] * p[7];
    for (int i = 8; i < 128; i += 8) {
        r0 = r0 + p[i + 0] * p[i + 0];
        r1 = r1 + p[i + 1] * p[i + 1];
        r2 = r2 + p[i + 2] * p[i + 2];
        r3 = r3 + p[i + 3] * p[i + 3];
        r4 = r4 + p[i + 4] * p[i + 4];
        r5 = r5 + p[i + 5] * p[i + 5];
        r6 = r6 + p[i + 6] * p[i + 6];
        r7 = r7 + p[i + 7] * p[i + 7];
    }
    return ((r0 + r1) + (r2 + r3)) + ((r4 + r5) + (r6 + r7));
}

__device__ __forceinline__ float np_pairwise256_sumsq(const float* a) {
    #pragma clang fp contract(off)
    float s0 = np_block128_sumsq(a);
    float s1 = np_block128_sumsq(a + 128);
    return s0 + s1;
}

// ---------------------------------------------------------------------------
// Kernel 1: per-row sum of squares, numpy-pairwise-exact (unchanged, verified)
// ---------------------------------------------------------------------------
__global__ __launch_bounds__(256) void rowsumsq(const float* __restrict__ A,
                                                float* __restrict__ out) {
    __shared__ __align__(16) float sA[MT][RSTRIDE];
    const int tid = threadIdx.x;
    const int base = blockIdx.x * MT;
    #pragma unroll
    for (int i = 0; i < 16; ++i) {
        int g = i * 256 + tid;
        int row = g >> 6, d4 = g & 63;
        float4 v = reinterpret_cast<const float4*>(A)[(size_t)(base + row) * (DD / 4) + d4];
        *reinterpret_cast<float4*>(&sA[row][d4 * 4]) = v;
    }
    __syncthreads();
    if (tid < MT) out[base + tid] = np_pairwise256_sumsq(sA[tid]);
}

// ---------------------------------------------------------------------------
// Kernel 2: main VQ kernel. 256 blocks x 256 threads, 1 block/CU.
//   16x8 register tile, C XOR-rotated in LDS (round 7, verified bit-exact).
//   NEW: explicit 2-deep operand pipeline — cc[2][8]/xr[2][16] so the LDS
//   loads of d4-step n+1 issue during the fma burst of step n. With only
//   1 wave/SIMD there is no TLP; this supplies the ILP the compiler didn't
//   (round-7 timeline: per-epoch 11.8k cyc vs 4.8k pipe need = exposed
//   lgkmcnt(0) waits each d4 step).
//   fp32 fma chain per (row,col) strictly d=0..255 -> bit-exact (verified),
//   score fl(fl(x2+c2)-2m) + first-index ties.
// ---------------------------------------------------------------------------
__global__ __launch_bounds__(256, 1) void vq_main(const float* __restrict__ X,
                                                  const float* __restrict__ CB,
                                                  const float* __restrict__ c2,
                                                  const float* __restrict__ x2,
                                                  const float* __restrict__ mask,
                                                  float* __restrict__ out,
                                                  float* __restrict__ hist,
                                                  float* __restrict__ partial) {
    __shared__ __align__(16) float sX[NDT * MT * DT];  // 65536 B
    __shared__ __align__(16) float sC[2 * CBUF];       // 65536 B
    __shared__ int   row_id[MT];
    __shared__ float wsum[4];

    const int tid  = threadIdx.x;
    const int lane = tid & 63;
    const int wid  = tid >> 6;                                  // wave id (compute)
    const int widu = __builtin_amdgcn_readfirstlane(tid >> 6);  // uniform (staging dst)
    const int block_row = blockIdx.x * MT;

    // ---- stage X (once): 64 calls, 16/wave. Plain layout sX[(dt*64+row)*16+f] ----
    #pragma unroll
    for (int k = 0; k < 16; ++k) {
        unsigned call = widu * 16u + k;
        unsigned rowp = call * 16u + (lane >> 2);   // flat 16B-unit >> 2 = dt*64+row
        unsigned p    = lane & 3u;
        unsigned dt   = rowp >> 6, row = rowp & 63u;
        gl2lds16(X + (size_t)(block_row + row) * DD + dt * DT + p * 4u,
                 &sX[call * 256]);
    }

    // ---- C staging: per-lane invariant source offsets (swizzle on source) ----
    // LDS unit U = call*64+lane; row c = U>>2; pos p = U&3 holds logical
    // d4 = (p - (c>>3)) & 3  ->  read side: unit = c*4 + ((d4 + (c>>3)) & 3).
    unsigned invf[8];
    #pragma unroll
    for (int k = 0; k < 8; ++k) {
        unsigned call = widu * 8u + k;
        unsigned c   = call * 16u + (lane >> 2);    // 0..511
        unsigned p   = lane & 3u;
        unsigned d4l = (p - (c >> 3)) & 3u;
        invf[k] = c * DD + d4l * 4u;
    }
    // stage epoch 0 (ch 0, dt 0) into buf 0
    #pragma unroll
    for (int k = 0; k < 8; ++k)
        gl2lds16(CB + invf[k], &sC[(widu * 8u + k) * 256]);

    // row constants (bit-identical to numpy's x2)
    float x2r[16];
    #pragma unroll
    for (int rr = 0; rr < 16; ++rr) x2r[rr] = x2[block_row + wid * 16 + rr];

    __syncthreads();   // drains vmcnt -> sX + sC buf0 resident

    float best[16];
    int   besti[16];
    #pragma unroll
    for (int rr = 0; rr < 16; ++rr) { best[rr] = 3.4e38f; besti[rr] = 0; }

    for (int ch = 0; ch < NCH; ++ch) {
        float c2v[8];
        #pragma unroll
        for (int j = 0; j < 8; ++j) c2v[j] = c2[ch * NT + lane + 64 * j];

        float acc[16][8];
        #pragma unroll
        for (int rr = 0; rr < 16; ++rr)
            #pragma unroll
            for (int j = 0; j < 8; ++j) acc[rr][j] = 0.0f;

        for (int dt = 0; dt < NDT; ++dt) {
            const int e = ch * NDT + dt;

            // ---- async-stage next slice into the other buffer ----
            if (e + 1 < NEPOCH) {
                const int nch = (e + 1) >> 4, ndt = (e + 1) & 15;
                const size_t so = (size_t)nch * NT * DD + (size_t)ndt * DT;
                float* dst = &sC[((e + 1) & 1) * CBUF];
                #pragma unroll
                for (int k = 0; k < 8; ++k)
                    gl2lds16(CB + so + invf[k], dst + (widu * 8u + k) * 256);
            }

            // ---- compute on current buffer: 2-deep operand pipeline ----
            const float* cb_ = &sC[(e & 1) * CBUF] + lane * DT;
            const float* xb_ = &sX[(dt * MT + wid * 16) * DT];

            float4 cc[2][8], xr[2][16];
            // preload d4 = 0
            {
                const unsigned pos0 = (0 + (lane >> 3)) & 3u;
                #pragma unroll
                for (int j = 0; j < 8; ++j)
                    cc[0][j] = *reinterpret_cast<const float4*>(cb_ + j * 64 * DT + pos0 * 4);
                #pragma unroll
                for (int rr = 0; rr < 16; ++rr)
                    xr[0][rr] = *reinterpret_cast<const float4*>(xb_ + rr * DT + 0 * 4);
            }
            #pragma unroll
            for (int d4 = 0; d4 < 4; ++d4) {
                const int cur = d4 & 1, nxt = cur ^ 1;
                // issue next step's loads before this step's fma burst
                if (d4 + 1 < 4) {
                    const unsigned posn = ((d4 + 1) + (lane >> 3)) & 3u;
                    #pragma unroll
                    for (int j = 0; j < 8; ++j)
                        cc[nxt][j] = *reinterpret_cast<const float4*>(cb_ + j * 64 * DT + posn * 4);
                    #pragma unroll
                    for (int rr = 0; rr < 16; ++rr)
                        xr[nxt][rr] = *reinterpret_cast<const float4*>(xb_ + rr * DT + (d4 + 1) * 4);
                }
                #pragma unroll
                for (int rr = 0; rr < 16; ++rr)
                    #pragma unroll
                    for (int j = 0; j < 8; ++j) {
                        acc[rr][j] = fmaf(xr[cur][rr].x, cc[cur][j].x, acc[rr][j]);
                        acc[rr][j] = fmaf(xr[cur][rr].y, cc[cur][j].y, acc[rr][j]);
                        acc[rr][j] = fmaf(xr[cur][rr].z, cc[cur][j].z, acc[rr][j]);
                        acc[rr][j] = fmaf(xr[cur][rr].w, cc[cur][j].w, acc[rr][j]);
                    }
            }
            __syncthreads();   // next-slice DMA drained; buf safe to recycle
        }

        // ---- fp32 distance exactly as numpy, then argmin (first-index ties) ----
        #pragma unroll
        for (int rr = 0; rr < 16; ++rr) {
            #pragma unroll
            for (int j = 0; j < 8; ++j) {
                int col = ch * NT + lane + 64 * j;
                float t1 = x2r[rr] + c2v[j];
                float s  = t1 - 2.0f * acc[rr][j];
                if (s < best[rr] || (s == best[rr] && col < besti[rr])) {
                    best[rr] = s; besti[rr] = col;
                }
            }
        }
    }

    // ---- per-row argmin across the wave's 64 lanes (xor butterfly) ----
    #pragma unroll
    for (int rr = 0; rr < 16; ++rr) {
        float b = best[rr];
        int  bi = besti[rr];
        #pragma unroll
        for (int m = 32; m > 0; m >>= 1) {
            float b2 = __shfl_xor(b, m, 64);
            int   i2 = __shfl_xor(bi, m, 64);
            if (b2 < b || (b2 == b && i2 < bi)) { b = b2; bi = i2; }
        }
        if (lane == 0) row_id[wid * 16 + rr] = bi;
    }
    __syncthreads();

    if (tid < MT) {
        int bi = row_id[tid];
        out[OUT_IDS + block_row + tid] = (float)bi;
        atomicAdd(&hist[bi], mask[block_row + tid]);
    }

    // ---- fused gather: quantized, st_quantized, MSE partial (x from global) ----
    float msep = 0.0f;
    float* outq  = out + OUT_Q;
    float* outst = out + OUT_ST;
    #pragma unroll
    for (int i = 0; i < 16; ++i) {
        int g = i * 256 + tid;
        int row = g >> 6;
        int d4  = g & 63;
        int id = row_id[row];
        float4 q = reinterpret_cast<const float4*>(CB)[(size_t)id * (DD / 4) + d4];
        float4 x = reinterpret_cast<const float4*>(X)[(size_t)(block_row + row) * (DD / 4) + d4];
        float4 st;
        st.x = x.x + (q.x - x.x);
        st.y = x.y + (q.y - x.y);
        st.z = x.z + (q.z - x.z);
        st.w = x.w + (q.w - x.w);
        float dx = x.x - q.x; msep = fmaf(dx, dx, msep);
        dx = x.y - q.y; msep = fmaf(dx, dx, msep);
        dx = x.z - q.z; msep = fmaf(dx, dx, msep);
        dx = x.w - q.w; msep = fmaf(dx, dx, msep);
        size_t o = (size_t)(block_row + row) * (DD / 4) + d4;
        reinterpret_cast<float4*>(outq)[o]  = q;
        reinterpret_cast<float4*>(outst)[o] = st;
    }
    #pragma unroll
    for (int off = 32; off > 0; off >>= 1) msep += __shfl_down(msep, off, 64);
    if (lane == 0) wsum[wid] = msep;
    __syncthreads();
    if (tid == 0) partial[blockIdx.x] = wsum[0] + wsum[1] + wsum[2] + wsum[3];
}

// ---------------------------------------------------------------------------
// Kernel 3: finalize losses + perplexity (double precision, single block)
// ---------------------------------------------------------------------------
__global__ __launch_bounds__(256) void vq_finalize(const float* __restrict__ partial,
                                                   const float* __restrict__ hist,
                                                   float* __restrict__ out) {
    __shared__ double red[256];
    const int tid = threadIdx.x;

    double ps = 0.0;
    for (int j = tid; j < NBLOCKS; j += 256) ps += (double)partial[j];
    red[tid] = ps;
    __syncthreads();
    for (int s = 128; s > 0; s >>= 1) {
        if (tid < s) red[tid] += red[tid + s];
        __syncthreads();
    }
    double mse_sum = red[0];
    __syncthreads();

    double hs = 0.0;
    for (int j = tid; j < KK; j += 256) hs += (double)hist[j];
    red[tid] = hs;
    __syncthreads();
    for (int s = 128; s > 0; s >>= 1) {
        if (tid < s) red[tid] += red[tid + s];
        __syncthreads();
    }
    double denom = red[0] > 1.0 ? red[0] : 1.0;
    __syncthreads();

    double ent = 0.0;
    for (int j = tid; j < KK; j += 256) {
        double p = (double)hist[j] / denom;
        ent += p * log(p + 1e-8);
    }
    red[tid] = ent;
    __syncthreads();
    for (int s = 128; s > 0; s >>= 1) {
        if (tid < s) red[tid] += red[tid + s];
        __syncthreads();
    }

    if (tid == 0) {
        double mse = mse_sum / (double)((size_t)NN * DD);
        out[OUT_COMMIT] = (float)(mse * 0.25);
        out[OUT_CBL]    = (float)mse;
        out[OUT_PERP]   = (float)exp(-red[0]);
    }
}

// ---------------------------------------------------------------------------
extern "C" void kernel_launch(void* const* d_in, const int* in_sizes, int n_in,
                              void* d_out, int out_size, void* d_ws, size_t ws_size,
                              hipStream_t stream) {
    const float* latents = (const float*)d_in[0];   // [16,1024,256]
    const float* mask    = (const float*)d_in[1];   // [16,1024]
    const float* cb      = (const float*)d_in[2];   // [8192,256]
    float* out = (float*)d_out;

    // workspace layout (floats): hist[8192] | partial[256] | c2[8192] | x2[16384]
    float* hist    = (float*)d_ws;
    float* partial = hist + KK;
    float* c2      = partial + NBLOCKS;
    float* x2      = c2 + KK;

    hipMemsetAsync(d_ws, 0, KK * sizeof(float), stream);   // zero histogram
    rowsumsq<<<KK / MT, 256, 0, stream>>>(cb, c2);          // numpy-exact |c|^2
    rowsumsq<<<NN / MT, 256, 0, stream>>>(latents, x2);     // numpy-exact |x|^2
    vq_main<<<NBLOCKS, 256, 0, stream>>>(latents, cb, c2, x2, mask, out, hist, partial);
    vq_finalize<<<1, 256, 0, stream>>>(partial, hist, out);
}

// Round 9
// 1136.087 us; speedup vs baseline: 1.1003x; 1.1003x over previous
//
#include <hip/hip_runtime.h>
#include <math.h>

// Problem constants
#define DD 256            // latent dim
#define KK 8192           // codebook size
#define NN 16384          // rows
#define MT 32             // rows per block (4 waves x 8 rows)
#define RPW 8             // rows per wave
#define NT 512            // codebook cols per chunk (lane + 64*j, j 0..7)
#define NCH (KK / NT)     // 16 chunks
#define DT 8              // d-slice floats (2 d4-units)
#define NSL (DD / DT)     // 32 slices per chunk
#define NEPOCH (NCH * NSL)  // 512
#define NBLOCKS (NN / MT) // 512  -> 2 blocks/CU, 2 waves/SIMD
#define CBUFF 4096        // floats per C buffer (512 cols x 8) = 16 KB
#define RSTRIDE 260       // rowsumsq staging stride (unchanged, verified)

// Output layout (all float32, concatenated in reference return order)
#define OUT_IDS   0
#define OUT_Q     16384
#define OUT_ST    4210688          // 16384 + 4194304
#define OUT_COMMIT 8404992
#define OUT_CBL    8404993
#define OUT_PERP   8404994

// ---------------------------------------------------------------------------
// async global->LDS DMA: lane i's 16B lands at ldsbase + i*16 (contiguous 1KB).
// Global source address is PER-LANE -> layout shuffles live on the source side.
// ---------------------------------------------------------------------------
__device__ __forceinline__ void gl2lds16(const float* g, float* l) {
    __builtin_amdgcn_global_load_lds(
        (const __attribute__((address_space(1))) float*)g,
        (__attribute__((address_space(3))) float*)l, 16, 0, 0);
}

// readlane: pull a float from a given lane into an SGPR (uniform). Bit-exact.
__device__ __forceinline__ float rlane(float v, int l) {
    return __int_as_float(__builtin_amdgcn_readlane(__float_as_int(v), l));
}

// ---------------------------------------------------------------------------
// numpy pairwise-sum replica for sum of squares (verified bit-exact, round 2)
// ---------------------------------------------------------------------------
__device__ __forceinline__ float np_block128_sumsq(const float* p) {
    #pragma clang fp contract(off)
    float r0 = p[0] * p[0], r1 = p[1] * p[1], r2 = p[2] * p[2], r3 = p[3] * p[3];
    float r4 = p[4] * p[4], r5 = p[5] * p[5], r6 = p[6] * p[6], r7 = p[7] * p[7];
    for (int i = 8; i < 128; i += 8) {
        r0 = r0 + p[i + 0] * p[i + 0];
        r1 = r1 + p[i + 1] * p[i + 1];
        r2 = r2 + p[i + 2] * p[i + 2];
        r3 = r3 + p[i + 3] * p[i + 3];
        r4 = r4 + p[i + 4] * p[i + 4];
        r5 = r5 + p[i + 5] * p[i + 5];
        r6 = r6 + p[i + 6] * p[i + 6];
        r7 = r7 + p[i + 7] * p[i + 7];
    }
    return ((r0 + r1) + (r2 + r3)) + ((r4 + r5) + (r6 + r7));
}

__device__ __forceinline__ float np_pairwise256_sumsq(const float* a) {
    #pragma clang fp contract(off)
    float s0 = np_block128_sumsq(a);
    float s1 = np_block128_sumsq(a + 128);
    return s0 + s1;
}

// ---------------------------------------------------------------------------
// Kernel 1: per-row sum of squares, numpy-pairwise-exact (unchanged, verified)
// ---------------------------------------------------------------------------
__global__ __launch_bounds__(256) void rowsumsq(const float* __restrict__ A,
                                                float* __restrict__ out) {
    __shared__ __align__(16) float sA[64][RSTRIDE];
    const int tid = threadIdx.x;
    const int base = blockIdx.x * 64;
    #pragma unroll
    for (int i = 0; i < 16; ++i) {
        int g = i * 256 + tid;
        int row = g >> 6, d4 = g & 63;
        float4 v = reinterpret_cast<const float4*>(A)[(size_t)(base + row) * (DD / 4) + d4];
        *reinterpret_cast<float4*>(&sA[row][d4 * 4]) = v;
    }
    __syncthreads();
    if (tid < 64) out[base + tid] = np_pairwise256_sumsq(sA[tid]);
}

// ---------------------------------------------------------------------------
// Kernel 2: main VQ kernel. 512 blocks x 256 threads, 2 blocks/CU (TLP!).
//   Wave owns 8 rows x all cols. 8x8 register tile over NT=512 (col=lane+64j).
//   X: one ds_read_b128 loads an 8-row x 8-d4 super-block across lanes; the
//   per-step X values come from v_readlane (VALU->SGPR, the fma's scalar
//   operand) -> DS traffic is cc-only (8 b128/step, lane-linear, no conflicts,
//   all-immediate offsets). C streamed in 512x8 slices, double-buffered DMA,
//   d4-plane-major layout (unit = d4l*512 + col).
//   fp32 fma chain per (row,col) strictly d=0..255 -> bit-exact (verified),
//   score fl(fl(x2+c2)-2m) + first-index ties.
// ---------------------------------------------------------------------------
__global__ __launch_bounds__(256, 2) void vq_main(const float* __restrict__ X,
                                                  const float* __restrict__ CB,
                                                  const float* __restrict__ c2,
                                                  const float* __restrict__ x2,
                                                  const float* __restrict__ mask,
                                                  float* __restrict__ out,
                                                  float* __restrict__ hist,
                                                  float* __restrict__ partial) {
    __shared__ __align__(16) float sX[8192];        // 32 KB: 4 waves x 8 rows x 256d
    __shared__ __align__(16) float sC[2 * CBUFF];   // 32 KB: double-buffered C slice
    __shared__ int   row_id[MT];
    __shared__ float wsum[4];

    const int tid  = threadIdx.x;
    const int lane = tid & 63;
    const int wid  = tid >> 6;                                  // compute path
    const int widu = __builtin_amdgcn_readfirstlane(wid);       // staging dst (uniform)
    const int block_row = blockIdx.x * MT;

    // ---- stage X: 8 calls/wave. Superblock k holds rows 0..7 x d4 k*8..k*8+7:
    //      staging lane L writes unit L = (d4rel=L>>3, rr=L&7) so the compute
    //      read (lane L -> its own unit) is linear/conflict-free.
    {
        const unsigned rr = lane & 7u, d4r = lane >> 3;
        #pragma unroll
        for (int k = 0; k < 8; ++k)
            gl2lds16(X + (size_t)(block_row + widu * 8 + rr) * DD + k * 32 + d4r * 4,
                     &sX[(widu * 8 + k) * 256]);
    }

    // ---- C staging source offsets: unit u = d4plane*512 + col (4 calls/wave) ----
    unsigned coff[4];
    #pragma unroll
    for (int k = 0; k < 4; ++k) {
        unsigned u  = (widu * 4u + (unsigned)k) * 64u + (unsigned)lane;
        unsigned c  = u & 511u;
        unsigned pl = u >> 9;
        coff[k] = c * DD + pl * 4u;
    }
    #pragma unroll
    for (int k = 0; k < 4; ++k)     // epoch 0 (ch0, sl0) -> buf 0
        gl2lds16(CB + coff[k], &sC[(widu * 4 + k) * 256]);

    // row constants (bit-identical to numpy's x2)
    float x2r[RPW];
    #pragma unroll
    for (int rr = 0; rr < RPW; ++rr) x2r[rr] = x2[block_row + wid * RPW + rr];

    __syncthreads();   // drains vmcnt -> sX + sC buf0 resident

    float best[RPW];
    int   besti[RPW];
    #pragma unroll
    for (int rr = 0; rr < RPW; ++rr) { best[rr] = 3.4e38f; besti[rr] = 0; }

    for (int ch = 0; ch < NCH; ++ch) {
        float c2v[8];
        #pragma unroll
        for (int j = 0; j < 8; ++j) c2v[j] = c2[ch * NT + lane + 64 * j];

        float acc[8][8];
        #pragma unroll
        for (int rr = 0; rr < 8; ++rr)
            #pragma unroll
            for (int j = 0; j < 8; ++j) acc[rr][j] = 0.0f;

        float4 xp;   // current X super-block (reloaded every 4 slices)

        #pragma unroll 4
        for (int sl = 0; sl < NSL; ++sl) {
            const int e = ch * NSL + sl;

            // ---- async-stage next C slice into the other buffer ----
            if (e + 1 < NEPOCH) {
                const int nch = (e + 1) >> 5, nsl = (e + 1) & 31;
                const float* so = CB + (size_t)nch * (NT * DD) + nsl * DT;
                float* dst = &sC[((e + 1) & 1) * CBUFF];
                #pragma unroll
                for (int k = 0; k < 4; ++k)
                    gl2lds16(so + coff[k], dst + (widu * 4 + k) * 256);
            }

            // ---- X super-block: one b128 per 8 d4-steps ----
            if ((sl & 3) == 0) {
                const int b = sl >> 2;
                xp = *reinterpret_cast<const float4*>(&sX[(wid * 8 + b) * 256 + lane * 4]);
            }

            // ---- compute: 2 d4-steps on current buffer ----
            const float* cb_ = &sC[(e & 1) * CBUFF] + lane * 4;
            #pragma unroll
            for (int s = 0; s < 2; ++s) {
                const int t = (sl & 3) * 2 + s;          // d4 within super-block
                float4 cc[8];
                #pragma unroll
                for (int j = 0; j < 8; ++j)
                    cc[j] = *reinterpret_cast<const float4*>(cb_ + s * 2048 + j * 256);
                #pragma unroll
                for (int rr = 0; rr < 8; ++rr) {
                    const int rl = t * 8 + rr;           // lane holding X[rr][d4]
                    const float sx = rlane(xp.x, rl);
                    const float sy = rlane(xp.y, rl);
                    const float sz = rlane(xp.z, rl);
                    const float sw = rlane(xp.w, rl);
                    #pragma unroll
                    for (int j = 0; j < 8; ++j) {
                        acc[rr][j] = fmaf(sx, cc[j].x, acc[rr][j]);
                        acc[rr][j] = fmaf(sy, cc[j].y, acc[rr][j]);
                        acc[rr][j] = fmaf(sz, cc[j].z, acc[rr][j]);
                        acc[rr][j] = fmaf(sw, cc[j].w, acc[rr][j]);
                    }
                }
            }
            __syncthreads();   // reads of cur buf done; next-slice DMA drained
        }

        // ---- fp32 distance exactly as numpy, then argmin (first-index ties) ----
        #pragma unroll
        for (int rr = 0; rr < 8; ++rr) {
            #pragma unroll
            for (int j = 0; j < 8; ++j) {
                const int col = ch * NT + lane + 64 * j;
                float t1 = x2r[rr] + c2v[j];
                float sc = t1 - 2.0f * acc[rr][j];
                if (sc < best[rr] || (sc == best[rr] && col < besti[rr])) {
                    best[rr] = sc; besti[rr] = col;
                }
            }
        }
    }

    // ---- per-row argmin across the wave's 64 lanes (xor butterfly) ----
    #pragma unroll
    for (int rr = 0; rr < RPW; ++rr) {
        float b = best[rr];
        int  bi = besti[rr];
        #pragma unroll
        for (int m = 32; m > 0; m >>= 1) {
            float b2 = __shfl_xor(b, m, 64);
            int   i2 = __shfl_xor(bi, m, 64);
            if (b2 < b || (b2 == b && i2 < bi)) { b = b2; bi = i2; }
        }
        if (lane == 0) row_id[wid * RPW + rr] = bi;
    }
    __syncthreads();

    if (tid < MT) {
        int bi = row_id[tid];
        out[OUT_IDS + block_row + tid] = (float)bi;
        atomicAdd(&hist[bi], mask[block_row + tid]);
    }

    // ---- fused gather: quantized, st_quantized, MSE partial ----
    float msep = 0.0f;
    float* outq  = out + OUT_Q;
    float* outst = out + OUT_ST;
    #pragma unroll
    for (int i = 0; i < 8; ++i) {
        int g = i * 256 + tid;          // 0..2047 covers 32 rows x 64 float4
        int row = g >> 6;
        int d4  = g & 63;
        int id  = row_id[row];
        float4 q = reinterpret_cast<const float4*>(CB)[(size_t)id * (DD / 4) + d4];
        float4 x = reinterpret_cast<const float4*>(X)[(size_t)(block_row + row) * (DD / 4) + d4];
        float4 st;
        st.x = x.x + (q.x - x.x);
        st.y = x.y + (q.y - x.y);
        st.z = x.z + (q.z - x.z);
        st.w = x.w + (q.w - x.w);
        float dx = x.x - q.x; msep = fmaf(dx, dx, msep);
        dx = x.y - q.y; msep = fmaf(dx, dx, msep);
        dx = x.z - q.z; msep = fmaf(dx, dx, msep);
        dx = x.w - q.w; msep = fmaf(dx, dx, msep);
        size_t o = (size_t)(block_row + row) * (DD / 4) + d4;
        reinterpret_cast<float4*>(outq)[o]  = q;
        reinterpret_cast<float4*>(outst)[o] = st;
    }
    #pragma unroll
    for (int off = 32; off > 0; off >>= 1) msep += __shfl_down(msep, off, 64);
    if (lane == 0) wsum[wid] = msep;
    __syncthreads();
    if (tid == 0) partial[blockIdx.x] = wsum[0] + wsum[1] + wsum[2] + wsum[3];
}

// ---------------------------------------------------------------------------
// Kernel 3: finalize losses + perplexity (double precision, single block)
// ---------------------------------------------------------------------------
__global__ __launch_bounds__(256) void vq_finalize(const float* __restrict__ partial,
                                                   const float* __restrict__ hist,
                                                   float* __restrict__ out) {
    __shared__ double red[256];
    const int tid = threadIdx.x;

    double ps = 0.0;
    for (int j = tid; j < NBLOCKS; j += 256) ps += (double)partial[j];
    red[tid] = ps;
    __syncthreads();
    for (int s = 128; s > 0; s >>= 1) {
        if (tid < s) red[tid] += red[tid + s];
        __syncthreads();
    }
    double mse_sum = red[0];
    __syncthreads();

    double hs = 0.0;
    for (int j = tid; j < KK; j += 256) hs += (double)hist[j];
    red[tid] = hs;
    __syncthreads();
    for (int s = 128; s > 0; s >>= 1) {
        if (tid < s) red[tid] += red[tid + s];
        __syncthreads();
    }
    double denom = red[0] > 1.0 ? red[0] : 1.0;
    __syncthreads();

    double ent = 0.0;
    for (int j = tid; j < KK; j += 256) {
        double p = (double)hist[j] / denom;
        ent += p * log(p + 1e-8);
    }
    red[tid] = ent;
    __syncthreads();
    for (int s = 128; s > 0; s >>= 1) {
        if (tid < s) red[tid] += red[tid + s];
        __syncthreads();
    }

    if (tid == 0) {
        double mse = mse_sum / (double)((size_t)NN * DD);
        out[OUT_COMMIT] = (float)(mse * 0.25);
        out[OUT_CBL]    = (float)mse;
        out[OUT_PERP]   = (float)exp(-red[0]);
    }
}

// ---------------------------------------------------------------------------
extern "C" void kernel_launch(void* const* d_in, const int* in_sizes, int n_in,
                              void* d_out, int out_size, void* d_ws, size_t ws_size,
                              hipStream_t stream) {
    const float* latents = (const float*)d_in[0];   // [16,1024,256]
    const float* mask    = (const float*)d_in[1];   // [16,1024]
    const float* cb      = (const float*)d_in[2];   // [8192,256]
    float* out = (float*)d_out;

    // workspace layout (floats): hist[8192] | partial[512] | c2[8192] | x2[16384]
    float* hist    = (float*)d_ws;
    float* partial = hist + KK;
    float* c2      = partial + NBLOCKS;
    float* x2      = c2 + KK;

    hipMemsetAsync(d_ws, 0, KK * sizeof(float), stream);   // zero histogram
    rowsumsq<<<KK / 64, 256, 0, stream>>>(cb, c2);          // numpy-exact |c|^2
    rowsumsq<<<NN / 64, 256, 0, stream>>>(latents, x2);     // numpy-exact |x|^2
    vq_main<<<NBLOCKS, 256, 0, stream>>>(latents, cb, c2, x2, mask, out, hist, partial);
    vq_finalize<<<1, 256, 0, stream>>>(partial, hist, out);
}